// Round 9
// baseline (18.041 us; speedup 1.0000x reference)
//
#include <hip/hip_runtime.h>
#include <math.h>

#define EPS_F 1.1920928955078125e-07f   // np.finfo(float32).eps

// cos/sin of k*pi/18, k=0..17 (correctly rounded f32; matches reference's
// linspace angles to <=2 ulp — threshold 2.6e-2 absorbs the drift)
__device__ __constant__ float CT[18] = {
    1.0f, 0.984807753f, 0.939692621f, 0.866025404f, 0.766044443f,
    0.642787610f, 0.5f, 0.342020143f, 0.173648178f, 0.0f,
    -0.173648178f, -0.342020143f, -0.5f, -0.642787610f, -0.766044443f,
    -0.866025404f, -0.939692621f, -0.984807753f };
__device__ __constant__ float ST[18] = {
    0.0f, 0.173648178f, 0.342020143f, 0.5f, 0.642787610f,
    0.766044443f, 0.866025404f, 0.939692621f, 0.984807753f, 1.0f,
    0.984807753f, 0.939692621f, 0.866025404f, 0.766044443f, 0.642787610f,
    0.5f, 0.342020143f, 0.173648178f };

__device__ __forceinline__ float rl(float v, int l) {   // uniform lane read -> SGPR
    return __int_as_float(__builtin_amdgcn_readlane(__float_as_int(v), l));
}

// ---- DPP helpers (VALU-latency cross-lane, exact integer semantics) ----
template <int CTRL>
__device__ __forceinline__ unsigned long long dpp_min_u64(unsigned long long best) {
    int lo = (int)(best & 0xFFFFFFFFULL), hi = (int)(best >> 32);
    int lo2 = __builtin_amdgcn_update_dpp(lo, lo, CTRL, 0xF, 0xF, false);
    int hi2 = __builtin_amdgcn_update_dpp(hi, hi, CTRL, 0xF, 0xF, false);
    unsigned long long o = ((unsigned long long)(unsigned)hi2 << 32) | (unsigned)lo2;
    return (o < best) ? o : best;
}
template <int CTRL, int RMASK>
__device__ __forceinline__ int dpp_max_i32(int v) {
    int o = __builtin_amdgcn_update_dpp(-1, v, CTRL, RMASK, 0xF, false);
    return (o > v) ? o : v;
}

// grid index q in [0,324) -> (a,b) in [0,18)^2  (magic-mul divide by 18)
__device__ __forceinline__ void decode_q(int q, int& a, int& b) {
    a = (q * 456) >> 13;        // == q/18 for 0 <= q < 324
    b = q - a * 18;
}

// Reconstruct the reference pair difference for grid point (a,b):
//   a<b : inner pair (a,b),       d = pts[b] - pts[a]
//   a>=b: cross pair (b, 18+a),   d = -pts[a] - pts[b]   (bit-exact rep)
// Also returns the ORIGINAL reference pair index m for tie-breaks.
__device__ __forceinline__ void pair_from_q(
    float xv, float yv, int q,
    float& dx, float& dy, int& m)
{
    int a, b; decode_q(q, a, b);
    float xA = __shfl(xv, a, 64), yA = __shfl(yv, a, 64);
    float xB = __shfl(xv, b, 64), yB = __shfl(yv, b, 64);
    bool inner = a < b;
    dx = inner ? (xB - xA) : (-(xA + xB));
    dy = inner ? (yB - yA) : (-(yA + yB));
    int i1 = inner ? a : b;
    int j1 = inner ? b : (a + 18);
    m = (i1 * (71 - i1)) / 2 + j1 - i1 - 1;
}

__device__ __forceinline__ float shoe4(float X0,float Y0,float X1,float Y1,
                                       float X2,float Y2,float X3,float Y3) {
    float s = 0.f;
    s += X0 * Y1 - Y0 * X1;
    s += X1 * Y2 - Y1 * X2;
    s += X2 * Y3 - Y2 * X3;
    s += X3 * Y0 - Y3 * X0;
    return 0.5f * fabsf(s);
}

__device__ __forceinline__ void scan_one(
    const float* PX, const float* PY, float xv, float yv, int q,
    unsigned long long& best)
{
    float dx, dy; int m;
    pair_from_q(xv, yv, q, dx, dy, m);
    float nrm = sqrtf(dx * dx + dy * dy);
    float inv = 1.f / fmaxf(nrm, 1e-9f);
    float ux = dx * inv, uy = dy * inv;
    float vx = -uy, vy = ux;
    float umax = 0.f, vmax = 0.f;   // max |proj| == fmax(pmax,-pmin) exactly
#pragma unroll
    for (int kk = 0; kk < 18; ++kk) {
        float x = PX[kk], y = PY[kk];
        float pu = ux * x + uy * y;
        float pv = vx * x + vy * y;
        umax = fmaxf(umax, fabsf(pu));
        vmax = fmaxf(vmax, fabsf(pv));
    }
    float area = (umax + umax) * (vmax + vmax);
    area = (nrm > 1e-9f) ? area : INFINITY;
    unsigned long long key =
        ((unsigned long long)__float_as_uint(area) << 32)
        | ((unsigned)m << 16) | (unsigned)q;
    if (key < best) best = key;
}

// balanced: wave sw owns q in [sw*81, sw*81+81); packed (area, m, q) min
__device__ __forceinline__ unsigned long long pair_scan(
    const float* PX, const float* PY, float xv, float yv, int lane, int sw)
{
    unsigned long long best = ~0ULL;
    const int q0 = sw * 81;
    scan_one(PX, PY, xv, yv, q0 + lane, best);
    if (lane < 17) scan_one(PX, PY, xv, yv, q0 + 64 + lane, best);
    // in-row rotate-reduce (integer min: order-invariant, exact)
    best = dpp_min_u64<0x121>(best);   // row_ror:1
    best = dpp_min_u64<0x122>(best);   // row_ror:2
    best = dpp_min_u64<0x124>(best);   // row_ror:4
    best = dpp_min_u64<0x128>(best);   // row_ror:8
    {
        unsigned long long o = __shfl_xor(best, 16, 64);
        if (o < best) best = o;
        o = __shfl_xor(best, 32, 64);
        if (o < best) best = o;
    }
    return best;
}

// finalize rect from winning key (low 16 bits = grid q); corners in CCW
// construction order (== reference's angle-sorted cycle up to rotation;
// shoelace and Sutherland-Hodgman are cyclic-rotation-invariant)
__device__ __forceinline__ void rect_finalize(
    const float* PX, const float* PY, float xv, float yv,
    unsigned long long key,
    float& c0x, float& c0y, float& c1x, float& c1y,
    float& c2x, float& c2y, float& c3x, float& c3y)
{
    int q = (int)(key & 0xFFFFULL);
    float dx, dy; int m_unused;
    pair_from_q(xv, yv, q, dx, dy, m_unused);
    float nrm = sqrtf(dx * dx + dy * dy);
    float inv = 1.f / fmaxf(nrm, 1e-9f);
    float ux = dx * inv, uy = dy * inv;
    float vx = -uy, vy = ux;
    float umax = 0.f, vmax = 0.f;
#pragma unroll
    for (int kk = 0; kk < 18; ++kk) {
        float x = PX[kk], y = PY[kk];
        float pu = ux * x + uy * y;
        float pv = vx * x + vy * y;
        umax = fmaxf(umax, fabsf(pu));
        vmax = fmaxf(vmax, fabsf(pv));
    }
    float umin = -umax, vmin = -vmax;
    c0x = umin * ux + vmin * vx;  c0y = umin * uy + vmin * vy;
    c1x = umax * ux + vmin * vx;  c1y = umax * uy + vmin * vy;
    c2x = umax * ux + vmax * vx;  c2y = umax * uy + vmax * vy;
    c3x = umin * ux + vmax * vx;  c3y = umin * uy + vmax * vy;
}

// one Sutherland-Hodgman step, literal lane-parallel copy of _clip_halfplane.
template <int K>
__device__ __forceinline__ void clip_step(float& x, float& y,
    float e1x, float e1y, float e2x, float e2y, int lane)
{
    const float dex = e2x - e1x, dey = e2y - e1y;
    float side = dex * (y - e1y) - dey * (x - e1x);
    int nl = (lane + 1) & (K - 1);
    float xn = __shfl(x, nl, 64);
    float yn = __shfl(y, nl, 64);
    float siden = __shfl(side, nl, 64);
    float denom = side - siden;
    float dd = (fabsf(denom) < 1e-12f) ? 1e-12f : denom;
    float t = side / dd;
    float ix = x + t * (xn - x);
    float iy = y + t * (yn - y);
    bool s_in = side >= 0.f, e_in = siden >= 0.f;
    int flags = (s_in ? 1 : 0) | (e_in ? 2 : 0);
    int src = lane >> 1;
    float ex  = __shfl(ix, src, 64);
    float ey  = __shfl(iy, src, 64);
    float nx2 = __shfl(xn, src, 64);
    float ny2 = __shfl(yn, src, 64);
    int   f2  = __shfl(flags, src, 64);
    bool odd = (lane & 1) != 0;
    float ox = odd ? nx2 : ex;
    float oy = odd ? ny2 : ey;
    bool sin2 = (f2 & 1) != 0, ein2 = (f2 & 2) != 0;
    bool vj = odd ? ein2 : (sin2 != ein2);
    vj = vj && (lane < 2 * K);
    int idx = vj ? lane : -1;
    idx = dpp_max_i32<0x111, 0xF>(idx);                  // row_shr:1
    idx = dpp_max_i32<0x112, 0xF>(idx);                  // row_shr:2
    idx = dpp_max_i32<0x114, 0xF>(idx);                  // row_shr:4
    if constexpr (2 * K > 8)  idx = dpp_max_i32<0x118, 0xF>(idx);  // row_shr:8
    if constexpr (2 * K > 16) idx = dpp_max_i32<0x142, 0xA>(idx);  // bcast15
    if constexpr (2 * K > 32) idx = dpp_max_i32<0x143, 0xC>(idx);  // bcast31
    unsigned long long bal = __ballot(vj);
    int firstv = (int)__ffsll(bal) - 1;
    int gi = (idx >= 0) ? idx : firstv;
    float gx = __shfl(ox, gi, 64);
    float gy = __shfl(oy, gi, 64);
    if (bal == 0ULL) { gx = 0.f; gy = 0.f; }
    x = gx; y = gy;
}

__global__ __launch_bounds__(512, 8) void iou_row_kernel(
    const float* __restrict__ output, const int* __restrict__ mask,
    const int* __restrict__ ind, const float* __restrict__ target,
    float* __restrict__ rowSl1, float* __restrict__ rowLi)
{
    const int row  = blockIdx.x;      // 0 .. 1023
    const int b    = row >> 6;
    const int tid  = threadIdx.x;
    const int lane = tid & 63;
    const int wid  = tid >> 6;        // 0..7
    const int poly = wid >> 2;        // waves 0-3 -> pred; 4-7 -> target
    const int sw   = wid & 3;

    __shared__ unsigned long long wkey[8];
    __shared__ float cXs[4], cYs[4];  // poly-1 corners
    __shared__ float s_sl1;

    const int idx = ind[row];
    float p = 0.f, t = 0.f, termv = 0.f, cosv = 0.f, sinv = 0.f;
    if (lane < 18) {
        cosv = CT[lane]; sinv = ST[lane];
        if (poly == 0) p = output[(size_t)(b * 18 + lane) * 65536 + idx];
        if (poly == 1 || wid == 0) t = target[row * 18 + lane];
        if (wid == 0) {
            float d = p - t, ad = fabsf(d);
            termv = (ad < 1.f) ? 0.5f * d * d : (ad - 0.5f);
        }
    }
    float base = (poly == 0) ? p : t;
    float xv = base * cosv, yv = base * sinv;

    // wave-uniform broadcast of the 18 base points via readlane (SGPR-resident)
    float PX[18], PY[18];
#pragma unroll
    for (int k = 0; k < 18; ++k) {
        PX[k] = rl(xv, k);
        PY[k] = rl(yv, k);
    }

    unsigned long long best = pair_scan(PX, PY, xv, yv, lane, sw);
    if (lane == 0) wkey[wid] = best;

    // wave 0: smooth-L1 mean, sequential order (readlane chain, exact)
    if (wid == 0) {
        float sl1 = 0.f;
#pragma unroll
        for (int k = 0; k < 18; ++k) sl1 += rl(termv, k);
        if (lane == 0) s_sl1 = sl1 / 18.0f;
    }
    __syncthreads();

    float ax0,ay0,ax1,ay1,ax2,ay2,ax3,ay3;
    if (sw == 0) {   // wave 0 finalizes poly 0, wave 4 finalizes poly 1
        unsigned long long k0 = wkey[4 * poly + 0], k1 = wkey[4 * poly + 1];
        unsigned long long k2 = wkey[4 * poly + 2], k3 = wkey[4 * poly + 3];
        unsigned long long ka = (k1 < k0) ? k1 : k0;
        unsigned long long kb = (k3 < k2) ? k3 : k2;
        unsigned long long kk = (kb < ka) ? kb : ka;
        rect_finalize(PX, PY, xv, yv, kk, ax0,ay0,ax1,ay1,ax2,ay2,ax3,ay3);
        if (wid == 4 && lane == 0) {
            cXs[0] = ax0; cYs[0] = ay0; cXs[1] = ax1; cYs[1] = ay1;
            cXs[2] = ax2; cYs[2] = ay2; cXs[3] = ax3; cYs[3] = ay3;
        }
    }
    __syncthreads();

    if (wid == 0) {
        float bx0 = cXs[0], by0 = cYs[0], bx1 = cXs[1], by1 = cYs[1];
        float bx2 = cXs[2], by2 = cYs[2], bx3 = cXs[3], by3 = cYs[3];

        float areaA = shoe4(ax0,ay0,ax1,ay1,ax2,ay2,ax3,ay3);
        float areaB = shoe4(bx0,by0,bx1,by1,bx2,by2,bx3,by3);

        int s3 = lane & 3;
        float px = (s3 == 0) ? ax0 : (s3 == 1) ? ax1 : (s3 == 2) ? ax2 : ax3;
        float py = (s3 == 0) ? ay0 : (s3 == 1) ? ay1 : (s3 == 2) ? ay2 : ay3;
        clip_step<4 >(px, py, bx0, by0, bx1, by1, lane);
        clip_step<8 >(px, py, bx1, by1, bx2, by2, lane);
        clip_step<16>(px, py, bx2, by2, bx3, by3, lane);
        clip_step<32>(px, py, bx3, by3, bx0, by0, lane);

        float xn = __shfl(px, (lane + 1) & 63, 64);
        float yn = __shfl(py, (lane + 1) & 63, 64);
        float term = px * yn - py * xn;
#pragma unroll
        for (int off = 1; off < 64; off <<= 1) term += __shfl_xor(term, off, 64);
        float inter = 0.5f * fabsf(term);

        float uni = areaA + areaB - inter;
        float iou = inter / fmaxf(uni, 1e-12f);

        if (lane == 0) {
            float sl1 = s_sl1;
            float mf = (float)mask[row];
            float alpha = -logf(fabsf(iou) + EPS_F);
            float li = alpha * sl1 / (fabsf(sl1) + EPS_F);
            rowSl1[row] = sl1 * mf;
            rowLi[row]  = li * mf;
        }
    }
}

__global__ __launch_bounds__(256) void iou_reduce_kernel(
    const float* __restrict__ rowSl1, const float* __restrict__ rowLi,
    const int* __restrict__ mask, float* __restrict__ out)
{
    __shared__ float s1[256], s2[256], s3[256];
    const int tid = threadIdx.x;
    float a = 0.f, c = 0.f, msum = 0.f;
    for (int i = tid; i < 1024; i += 256) {
        a += rowSl1[i];
        c += rowLi[i];
        msum += (float)mask[i];
    }
    s1[tid] = a; s2[tid] = c; s3[tid] = msum;
    __syncthreads();
    for (int off = 128; off > 0; off >>= 1) {
        if (tid < off) {
            s1[tid] += s1[tid + off];
            s2[tid] += s2[tid + off];
            s3[tid] += s3[tid + off];
        }
        __syncthreads();
    }
    if (tid == 0) {
        float cnt = fmaxf(s3[0], 1.0f);
        out[0] = s1[0] / cnt;
        out[1] = s2[0] / cnt;
    }
}

extern "C" void kernel_launch(void* const* d_in, const int* in_sizes, int n_in,
                              void* d_out, int out_size, void* d_ws, size_t ws_size,
                              hipStream_t stream) {
    const float* output = (const float*)d_in[0];
    const int*   mask   = (const int*)d_in[1];
    const int*   ind    = (const int*)d_in[2];
    const float* target = (const float*)d_in[3];
    float* out    = (float*)d_out;
    float* rowSl1 = (float*)d_ws;
    float* rowLi  = rowSl1 + 1024;

    iou_row_kernel<<<1024, 512, 0, stream>>>(output, mask, ind, target, rowSl1, rowLi);
    iou_reduce_kernel<<<1, 256, 0, stream>>>(rowSl1, rowLi, mask, out);
}